// Round 12
// baseline (164.465 us; speedup 1.0000x reference)
//
#include <hip/hip_runtime.h>
#include <math.h>

#define NB    128
#define NG    52
#define NGG   2704          // NG*NG = 42*64 + 16
#define NA    3
#define NCLS  15
#define NCH   20
#define PLANES (NB*NA)      // 384 (b,a) planes
#define WVP   43            // 64-cell chunks per plane (42 full + 16 tail)
#define NSLOT (PLANES*WVP)  // 16512 chunks
#define ITERS 8             // chunks per wave (16512 = 2064*8 exact)
#define NWAVE (NSLOT/ITERS) // 2064 waves
#define WPB   4
#define BLK   256
#define NBLK3 (NWAVE/WPB)   // 516 blocks
#define FPW   (64*NCH)      // 1280 floats per stage buffer (5 KB)
#define NPART NWAVE

typedef float f4 __attribute__((ext_vector_type(4)));

// async global->LDS DMA, 4 B/lane: lane l's word lands at lds + l*4 (vmcnt-tracked)
__device__ __forceinline__ void gload_lds(const float* g, float* l) {
    __builtin_amdgcn_global_load_lds(
        (const __attribute__((address_space(1))) void*)g,
        (__attribute__((address_space(3))) void*)l, 4, 0, 0);
}

// issue the 20 DMA loads for one chunk (exactly 20 vmcnt ops per wave, always)
__device__ __forceinline__ void stage_chunk(const float* __restrict__ x,
                                            int chunk, int l, float* buf) {
    int p   = chunk / WVP;
    int k   = chunk - p * WVP;
    int ji0 = k * 64;
    bool active = (ji0 + l < NGG);      // lanes 0..15 always active -> no execz skip
    const float* g = x + (size_t)p * (NCH * NGG) + ji0 + l;
    if (active) {
        #pragma unroll
        for (int c = 0; c < NCH; c++)
            gload_lds(g + c * NGG, buf + c * 64);
    }
}

// compute + restage + stores for one staged chunk (6..9 vmcnt store ops)
__device__ __forceinline__ void process_chunk(const float* __restrict__ labels,
                                              float* __restrict__ out,
                                              int chunk, int l,
                                              float* __restrict__ buf,
                                              float& tsum) {
    int p   = chunk / WVP;
    int k   = chunk - p * WVP;
    int b   = p / 3;
    int a   = p - b * 3;
    int ji0 = k * 64;
    int ji  = ji0 + l;
    bool active = (ji < NGG);
    int NACT = (NGG - ji0 < 64) ? (NGG - ji0) : 64;   // 64 or 16, wave-uniform
    int FACT = NACT * NCH;

    float z[NCH];
    #pragma unroll
    for (int c = 0; c < NCH; c++) z[c] = buf[c * 64 + l];

    float v[NCH];
    float conf = 1.0f / (1.0f + __expf(-z[4]));
    v[0] = 8.0f / (1.0f + __expf(-z[0]));
    v[1] = 8.0f / (1.0f + __expf(-z[1]));
    v[2] = 8.0f * z[2];
    v[3] = 8.0f * z[3];
    v[4] = conf;
    float m = z[5];
    #pragma unroll
    for (int c = 6; c < NCH; c++) m = fmaxf(m, z[c]);
    float s = 0.0f;
    #pragma unroll
    for (int c = 0; c < NCLS; c++) { v[5+c] = __expf(z[5+c] - m); s += v[5+c]; }
    float inv = 1.0f / s;
    #pragma unroll
    for (int c = 0; c < NCLS; c++) v[5+c] *= inv;

    // per-batch target logic (b,a wave-uniform)
    float gx = labels[b*5+0] * (float)NG;
    float gy = labels[b*5+1] * (float)NG;
    float gw = labels[b*5+2] * (float)NG;
    float gh = labels[b*5+3] * (float)NG;
    int  gcls = (int)labels[b*5+4];
    int gi = (int)gx, gj = (int)gy;
    float gwgh = gw * gh;
    float i0 = fminf(12.0f,   gw) * fminf(28.75f,  gh);
    float i1 = fminf(9.875f,  gw) * fminf(23.25f,  gh);
    float i2 = fminf(10.125f, gw) * fminf(16.625f, gh);
    float iou0 = i0 / (345.0f      + 1e-16f + gwgh - i0);
    float iou1 = i1 / (229.59375f  + 1e-16f + gwgh - i1);
    float iou2 = i2 / (168.328125f + 1e-16f + gwgh - i2);
    int best = 0; float bv = iou0;
    if (iou1 > bv) { best = 1; bv = iou1; }
    if (iou2 > bv) { best = 2; bv = iou2; }
    float ioua = (a == 0) ? iou0 : ((a == 1) ? iou1 : iou2);
    bool at_t   = (ji == gj * NG + gi);
    bool isbest = (a == best);

    if (active) {
        if (!(at_t && (isbest || ioua > 0.5f)))
            tsum += -100.0f * fmaxf(__logf(1.0f - conf), -100.0f);
        if (at_t && isbest) {
            tsum += -fmaxf(__logf(conf), -100.0f);
            float txv = gx - (float)gi;
            float tyv = gy - (float)gj;
            float abw = (best == 0) ? 12.0f  : ((best == 1) ? 9.875f : 10.125f);
            float abh = (best == 0) ? 28.75f : ((best == 1) ? 23.25f : 16.625f);
            float twv = __logf(gw / abw + 1e-16f);
            float thv = __logf(gh / abh + 1e-16f);
            tsum += fabsf(v[0]*0.125f - txv) + fabsf(v[1]*0.125f - tyv)
                  + fabsf(v[2]*0.125f - twv) + fabsf(v[3]*0.125f - thv);
            #pragma unroll
            for (int c = 0; c < NCLS; c++) {
                float pc = v[5+c];
                tsum += (c == gcls) ? -fmaxf(__logf(pc),        -100.0f)
                                    : -fmaxf(__logf(1.0f - pc), -100.0f);
            }
        }
    }

    // restage into same buffer (z reads drained first; wave-local)
    asm volatile("s_waitcnt lgkmcnt(0)" ::: "memory");
    if (active) {
        int base = l * NCH - 3;
        #pragma unroll
        for (int c = 0; c < NCH; c++) {
            int L = base + c;
            if (L < 0) L += FPW;               // only lane 0, c<3
            buf[L] = v[c];
        }
    }

    // wave-synchronous readback + coalesced plain f4 stores
    int NQ4w = (FACT - 4) / 4;                 // 319 or 79, wave-uniform
    int cell0 = p * NGG + ji0;
    size_t gf = 1 + (size_t)cell0 * NCH;       // 16B-aligned at gf+3
    f4* __restrict__ op = (f4*)(out + gf + 3);
    const f4* __restrict__ sp = (const f4*)buf;
    #pragma unroll
    for (int kk = 0; kk < 5; kk++) {
        int q = kk * 64 + l;
        if (q < NQ4w) op[q] = sp[q];
    }
    if (l == 0) {
        out[gf + 0]        = buf[FPW - 3];     // wrapped head 3 floats
        out[gf + 1]        = buf[FPW - 2];
        out[gf + 2]        = buf[FPW - 1];
        out[gf + FACT - 1] = buf[FACT - 4];    // tail scalar
    }
}

#define WAIT_VMCNT(n) do {                                         \
        asm volatile("s_waitcnt vmcnt(" #n ")" ::: "memory");      \
        __builtin_amdgcn_sched_barrier(0);                         \
    } while (0)

// ---- main: 8 chunks/wave, DMA double-buffer, counted vmcnt (never 0 mid-loop)
__global__ __launch_bounds__(BLK) void main_kernel(const float* __restrict__ x,
                                                   const float* __restrict__ labels,
                                                   float* __restrict__ out,
                                                   float* __restrict__ partials) {
    __shared__ __align__(16) float sm[WPB][2][FPW];   // 40 KB

    int t = threadIdx.x;
    int w = t >> 6;
    int l = t & 63;
    int wid   = blockIdx.x * WPB + w;
    int slot0 = wid * ITERS;
    float* __restrict__ b0 = &sm[w][0][0];
    float* __restrict__ b1 = &sm[w][1][0];
    float tsum = 0.0f;

    // prologue: DMA(0), DMA(1) in flight; wait only for DMA(0)
    stage_chunk(x, slot0 + 0, l, b0);                 // 20 vmem
    stage_chunk(x, slot0 + 1, l, b1);                 // 20 vmem
    WAIT_VMCNT(20);                                   // DMA(0) done, DMA(1) in flight
    process_chunk(labels, out, slot0 + 0, l, b0, tsum);   // 6..9 stores

    #pragma unroll
    for (int it = 1; it < ITERS - 1; ++it) {
        float* cur = (it & 1) ? b1 : b0;
        float* nxt = (it & 1) ? b0 : b1;
        stage_chunk(x, slot0 + it + 1, l, nxt);       // 20 vmem
        WAIT_VMCNT(26);                               // DMA(it) done (20 DMA + >=6 stores younger)
        process_chunk(labels, out, slot0 + it, l, cur, tsum);
    }

    // last chunk (ITERS-1 = 7, odd -> b1)
    WAIT_VMCNT(6);                                    // DMA(7) done (<=6 youngest stores allowed)
    process_chunk(labels, out, slot0 + ITERS - 1, l, b1, tsum);

    // wave reduce accumulated loss partial
    #pragma unroll
    for (int off = 32; off > 0; off >>= 1) tsum += __shfl_down(tsum, off, 64);
    if (l == 0) partials[wid] = tsum;
}

// ---- finish: deterministic reduction of 2064 per-wave partials ----
__global__ __launch_bounds__(1024) void finish_kernel(const float* __restrict__ partials,
                                                      float* __restrict__ out) {
    int t = threadIdx.x;
    float s = 0.0f;
    #pragma unroll
    for (int k = 0; k < NPART/1024 + 1; k++) {
        int q = k * 1024 + t;
        if (q < NPART) s += partials[q];
    }
    __shared__ float red[1024];
    red[t] = s;
    __syncthreads();
    for (int k = 512; k > 0; k >>= 1) {
        if (t < k) red[t] += red[t + k];
        __syncthreads();
    }
    if (t == 0) out[0] = red[0];
}

extern "C" void kernel_launch(void* const* d_in, const int* in_sizes, int n_in,
                              void* d_out, int out_size, void* d_ws, size_t ws_size,
                              hipStream_t stream) {
    const float* x      = (const float*)d_in[0];
    const float* labels = (const float*)d_in[1];
    float* out = (float*)d_out;
    float* ws  = (float*)d_ws;

    hipLaunchKernelGGL(main_kernel,   dim3(NBLK3), dim3(BLK),  0, stream, x, labels, out, ws);
    hipLaunchKernelGGL(finish_kernel, dim3(1),     dim3(1024), 0, stream, ws, out);
}

// Round 13
// 152.618 us; speedup vs baseline: 1.0776x; 1.0776x over previous
//
#include <hip/hip_runtime.h>
#include <math.h>

#define NB    128
#define NG    52
#define NGG   2704          // NG*NG
#define NA    3
#define NCLS  15
#define NCH   20
#define NQ    8112          // NA*NGG
#define TOTAL 1038336       // NB*NQ
#define BLK   256
#define NBLK  (TOTAL/BLK)   // 4056 (exact)
#define WPB   (BLK/64)      // 4 waves per block
#define FPW   (64*NCH)      // 1280 floats staged per wave
#define NPART (NBLK*WPB)    // 16224 per-wave partials

typedef float f4 __attribute__((ext_vector_type(4)));

// ---- main kernel: transform + loss terms; wave-synchronous restage, NO barriers
__global__ __launch_bounds__(BLK) void main_kernel(const float* __restrict__ x,
                                                   const float* __restrict__ labels,
                                                   float* __restrict__ out,
                                                   float* __restrict__ partials) {
    __shared__ __align__(16) float sm[WPB][FPW];   // private row per wave

    int t = threadIdx.x;
    int w = t >> 6;                   // wave id in block
    int l = t & 63;                   // lane
    int cell = blockIdx.x * BLK + t;  // one cell per thread
    int b  = cell / NQ;
    int r  = cell - b * NQ;
    int a  = r / NGG;
    int ji = r - a * NGG;

    const float* __restrict__ xp = x + ((size_t)(b*60 + a*20)) * NGG + ji;
    float z[NCH];
    #pragma unroll
    for (int c = 0; c < NCH; c++) z[c] = xp[c * NGG];

    float v[NCH];
    float conf = 1.0f / (1.0f + __expf(-z[4]));
    v[0] = 8.0f / (1.0f + __expf(-z[0]));
    v[1] = 8.0f / (1.0f + __expf(-z[1]));
    v[2] = 8.0f * z[2];
    v[3] = 8.0f * z[3];
    v[4] = conf;
    float m = z[5];
    #pragma unroll
    for (int c = 6; c < NCH; c++) m = fmaxf(m, z[c]);
    float s = 0.0f;
    #pragma unroll
    for (int c = 0; c < NCLS; c++) { v[5+c] = __expf(z[5+c] - m); s += v[5+c]; }
    float inv = 1.0f / s;
    #pragma unroll
    for (int c = 0; c < NCLS; c++) v[5+c] *= inv;

    // ---- per-batch target logic ----
    float gx = labels[b*5+0] * (float)NG;
    float gy = labels[b*5+1] * (float)NG;
    float gw = labels[b*5+2] * (float)NG;
    float gh = labels[b*5+3] * (float)NG;
    int  gcls = (int)labels[b*5+4];
    int gi = (int)gx, gj = (int)gy;
    float gwgh = gw * gh;
    float i0 = fminf(12.0f,   gw) * fminf(28.75f,  gh);
    float i1 = fminf(9.875f,  gw) * fminf(23.25f,  gh);
    float i2 = fminf(10.125f, gw) * fminf(16.625f, gh);
    float iou0 = i0 / (345.0f      + 1e-16f + gwgh - i0);   // 12*28.75
    float iou1 = i1 / (229.59375f  + 1e-16f + gwgh - i1);   // 9.875*23.25
    float iou2 = i2 / (168.328125f + 1e-16f + gwgh - i2);   // 10.125*16.625
    int best = 0; float bv = iou0;
    if (iou1 > bv) { best = 1; bv = iou1; }
    if (iou2 > bv) { best = 2; bv = iou2; }
    float ioua = (a == 0) ? iou0 : ((a == 1) ? iou1 : iou2);
    bool at_t   = (ji == gj * NG + gi);
    bool isbest = (a == best);

    float tsum = 0.0f;
    // noobj BCE term (x100), skipped where reference zeroes the noobj mask
    if (!(at_t && (isbest || ioua > 0.5f)))
        tsum = -100.0f * fmaxf(__logf(1.0f - conf), -100.0f);
    // obj terms at the best-anchor target cell
    if (at_t && isbest) {
        tsum += -fmaxf(__logf(conf), -100.0f);            // conf BCE, t=1
        float txv = gx - (float)gi;
        float tyv = gy - (float)gj;
        float abw = (best == 0) ? 12.0f  : ((best == 1) ? 9.875f : 10.125f);
        float abh = (best == 0) ? 28.75f : ((best == 1) ? 23.25f : 16.625f);
        float twv = __logf(gw / abw + 1e-16f);
        float thv = __logf(gh / abh + 1e-16f);
        tsum += fabsf(v[0]*0.125f - txv) + fabsf(v[1]*0.125f - tyv)
              + fabsf(v[2]*0.125f - twv) + fabsf(v[3]*0.125f - thv);
        #pragma unroll
        for (int c = 0; c < NCLS; c++) {
            float p = v[5+c];
            tsum += (c == gcls) ? -fmaxf(__logf(p),        -100.0f)
                                : -fmaxf(__logf(1.0f - p), -100.0f);
        }
    }

    // per-wave shifted LDS restage (wrap only for lane 0, c<3)
    float* __restrict__ smw = sm[w];
    int base = l * NCH - 3;
    #pragma unroll
    for (int c = 0; c < NCH; c++) {
        int L = base + c;
        if (L < 0) L += FPW;
        smw[L] = v[c];
    }

    // wave reduce loss partial (lane 0 ends with the wave sum)
    #pragma unroll
    for (int off = 32; off > 0; off >>= 1) tsum += __shfl_down(tsum, off, 64);

    // wave-synchronous readback: lanes are lockstep; compiler orders ds ops
    // (lgkmcnt drain) -- NO __syncthreads anywhere in this kernel.
    int cell0 = blockIdx.x * BLK + w * 64;                 // wave's first cell
    size_t gf = 1 + (size_t)cell0 * NCH;                   // first out float of wave region
    f4* __restrict__ op = (f4*)(out + gf + 3);             // 16B-aligned (gf+3 = 4+cell0*20)
    const f4* __restrict__ sp = (const f4*)smw;
    #pragma unroll
    for (int k = 0; k < 5; k++) {
        int q = k * 64 + l;
        if (q < (FPW - 4) / 4) op[q] = sp[q];   // plain stores (R10 A/B: beats NT by ~2.5us)
    }
    if (l == 0) {
        out[gf + 0]       = smw[FPW - 3];   // head 3 floats (wrapped)
        out[gf + 1]       = smw[FPW - 2];
        out[gf + 2]       = smw[FPW - 1];
        out[gf + FPW - 1] = smw[FPW - 4];   // tail scalar
        partials[blockIdx.x * WPB + w] = tsum;
    }
}

// ---- finish: deterministic reduction of 16224 per-wave partials ----
__global__ __launch_bounds__(1024) void finish_kernel(const float* __restrict__ partials,
                                                      float* __restrict__ out) {
    int t = threadIdx.x;   // 1024 threads
    float s = 0.0f;
    #pragma unroll
    for (int k = 0; k < NPART/1024 + 1; k++) {
        int q = k * 1024 + t;
        if (q < NPART) s += partials[q];
    }
    __shared__ float red[1024];
    red[t] = s;
    __syncthreads();
    for (int k = 512; k > 0; k >>= 1) {
        if (t < k) red[t] += red[t + k];
        __syncthreads();
    }
    if (t == 0) out[0] = red[0];
}

extern "C" void kernel_launch(void* const* d_in, const int* in_sizes, int n_in,
                              void* d_out, int out_size, void* d_ws, size_t ws_size,
                              hipStream_t stream) {
    const float* x      = (const float*)d_in[0];
    const float* labels = (const float*)d_in[1];
    float* out = (float*)d_out;
    float* ws  = (float*)d_ws;

    hipLaunchKernelGGL(main_kernel,   dim3(NBLK), dim3(BLK),  0, stream, x, labels, out, ws);
    hipLaunchKernelGGL(finish_kernel, dim3(1),    dim3(1024), 0, stream, ws, out);
}